// Round 5
// baseline (145.632 us; speedup 1.0000x reference)
//
#include <hip/hip_runtime.h>
#include <hip/hip_bf16.h>

typedef __attribute__((ext_vector_type(4))) float f32x4;
typedef __attribute__((ext_vector_type(8))) short s16x8;
typedef __attribute__((ext_vector_type(4))) unsigned int u32x4;

#define NODES 100000
#define SROW (NODES + 1)   // +1 zero row per slice for predication-free gathers
#define DIN 256
#define DOUT 128
#define NSLICE 8
#define SLICE_CH 16        // h_s[slice][SROW][16] bf16 = 3.2 MB/slice (fits 4MB XCD L2)

static __device__ inline unsigned short f2bf(float f) {
    __hip_bfloat16 h = __float2bfloat16(f);
    return __builtin_bit_cast(unsigned short, h);
}
static __device__ inline float lo2f(unsigned int v) {  // low bf16 -> f32
    return __builtin_bit_cast(float, v << 16);
}
static __device__ inline float hi2f(unsigned int v) {  // high bf16 -> f32
    return __builtin_bit_cast(float, v & 0xffff0000u);
}

// ---------------- prep: W fp32 -> bf16 ; inv_deg ; zero rows ----------------
__global__ __launch_bounds__(256) void gcn_prep(const float* __restrict__ W,
                                                const int* __restrict__ ptr,
                                                unsigned short* __restrict__ wsW,
                                                float* __restrict__ inv_deg,
                                                unsigned short* __restrict__ h_s) {
    int t = blockIdx.x * 256 + threadIdx.x;
    if (t < DOUT * DIN) wsW[t] = f2bf(W[t]);
    if (t < NODES) {
        int d = ptr[t + 1] - ptr[t];
        inv_deg[t] = d > 0 ? 1.0f / (float)d : 0.0f;
    }
    if (t < NSLICE * SLICE_CH)  // zero row (node index NODES) of each slice
        h_s[(long)(t >> 4) * (SROW * SLICE_CH) + (long)NODES * SLICE_CH + (t & 15)] = 0;
}

// ---------------- GEMM: h_s[slice][SROW][16] (bf16) = x @ W.T ---------------
// One wave per 32x128 tile. A straight from global x (fp32->bf16 in regs,
// next-k prefetched). B double-buffered in regs: LOADB(ks+1) issued before the
// MFMA step of ks so the ~200cyc L2 latency hides under compute (R3 had B
// un-prefetched on the critical path -> ~40us). MFMA 16x16x32 bf16;
// C/D: col=lane&15, row=(lane>>4)*4+reg. Output col-block n IS slice n.
#define LOADB(B, KS) \
    _Pragma("unroll") for (int n = 0; n < 8; ++n) \
        B[n] = *reinterpret_cast<const s16x8*>(wsW + (n * 16 + lr) * DIN + (KS) * 32 + lg * 8);

#define ASTEP(B, KS) { \
    f32x4 n00, n01, n10, n11; \
    if ((KS) < 7) { \
        n00 = *reinterpret_cast<const f32x4*>(xp0 + ((KS) + 1) * 32); \
        n01 = *reinterpret_cast<const f32x4*>(xp0 + ((KS) + 1) * 32 + 4); \
        n10 = *reinterpret_cast<const f32x4*>(xp1 + ((KS) + 1) * 32); \
        n11 = *reinterpret_cast<const f32x4*>(xp1 + ((KS) + 1) * 32 + 4); \
    } else { n00 = c00; n01 = c01; n10 = c10; n11 = c11; } \
    s16x8 a0, a1; \
    a0[0] = (short)f2bf(c00[0]); a0[1] = (short)f2bf(c00[1]); \
    a0[2] = (short)f2bf(c00[2]); a0[3] = (short)f2bf(c00[3]); \
    a0[4] = (short)f2bf(c01[0]); a0[5] = (short)f2bf(c01[1]); \
    a0[6] = (short)f2bf(c01[2]); a0[7] = (short)f2bf(c01[3]); \
    a1[0] = (short)f2bf(c10[0]); a1[1] = (short)f2bf(c10[1]); \
    a1[2] = (short)f2bf(c10[2]); a1[3] = (short)f2bf(c10[3]); \
    a1[4] = (short)f2bf(c11[0]); a1[5] = (short)f2bf(c11[1]); \
    a1[6] = (short)f2bf(c11[2]); a1[7] = (short)f2bf(c11[3]); \
    _Pragma("unroll") for (int n = 0; n < 8; ++n) { \
        acc[0][n] = __builtin_amdgcn_mfma_f32_16x16x32_bf16(a0, B[n], acc[0][n], 0, 0, 0); \
        acc[1][n] = __builtin_amdgcn_mfma_f32_16x16x32_bf16(a1, B[n], acc[1][n], 0, 0, 0); \
    } \
    c00 = n00; c01 = n01; c10 = n10; c11 = n11; }

__global__ __launch_bounds__(256) void gcn_gemm(const float* __restrict__ x,
                                                const unsigned short* __restrict__ wsW,
                                                unsigned short* __restrict__ h_s) {
    const int lane = threadIdx.x & 63;
    const int wid  = threadIdx.x >> 6;
    const int gwid = blockIdx.x * 4 + wid;
    const int row0 = gwid * 32;
    if (row0 >= NODES) return;
    const int lr = lane & 15;
    const int lg = lane >> 4;

    int r0 = row0 + lr;
    int r1 = row0 + 16 + lr;
    r0 = r0 < NODES ? r0 : NODES - 1;  // clamp; garbage rows never stored
    r1 = r1 < NODES ? r1 : NODES - 1;
    const float* xp0 = x + (long)r0 * DIN + lg * 8;
    const float* xp1 = x + (long)r1 * DIN + lg * 8;

    f32x4 acc[2][8];
#pragma unroll
    for (int m = 0; m < 2; ++m)
#pragma unroll
        for (int n = 0; n < 8; ++n) acc[m][n] = (f32x4)(0.0f);

    f32x4 c00 = *reinterpret_cast<const f32x4*>(xp0);
    f32x4 c01 = *reinterpret_cast<const f32x4*>(xp0 + 4);
    f32x4 c10 = *reinterpret_cast<const f32x4*>(xp1);
    f32x4 c11 = *reinterpret_cast<const f32x4*>(xp1 + 4);

    s16x8 bf[8], bn[8];
    LOADB(bf, 0);
    for (int ks2 = 0; ks2 < 8; ks2 += 2) {
        LOADB(bn, ks2 + 1);
        ASTEP(bf, ks2);
        if (ks2 < 6) LOADB(bf, ks2 + 2);
        ASTEP(bn, ks2 + 1);
    }

#pragma unroll
    for (int m = 0; m < 2; ++m) {
        const int rbase = row0 + m * 16 + lg * 4;
#pragma unroll
        for (int n = 0; n < 8; ++n) {
            const long sb = (long)n * (SROW * SLICE_CH);
#pragma unroll
            for (int r = 0; r < 4; ++r) {
                const int row = rbase + r;
                if (row < NODES)
                    h_s[sb + (long)row * SLICE_CH + lr] = f2bf(acc[m][n][r]);
            }
        }
    }
}

// ---------------- Aggregation: sliced, XCD-affine, sc0 pipelined ------------
// slice = blockIdx % 8 -> XCD-affine; gather set 3.2 MB L2-resident (verified
// R1-R3: FETCH == compulsory). R3 was L1-line-fill bound: each 32B row gather
// filled a 128B L1 line (4x L2->L1 amplification). Fix: buffer_load with sc0
// (L1 bypass, L2 allocate). Zero-row clamp (idx -> NODES if e >= deg) makes
// every gather unconditional; chunked counted-vmcnt pipeline keeps 16 gathers
// in flight. Wave = 32 nodes; lane = (g=lane>>1: node, c=lane&1: 8-ch half).
__global__ __launch_bounds__(320) void gcn_agg(const int* __restrict__ ptr,
                                               const int* __restrict__ idx,
                                               const unsigned short* __restrict__ h_s,
                                               const float* __restrict__ inv_deg,
                                               float* __restrict__ out, int E) {
    const int lane  = threadIdx.x & 63;
    const int wid   = threadIdx.x >> 6;           // 0..4
    const int slice = blockIdx.x & 7;
    const int chunk = blockIdx.x >> 3;            // 0..624
    const int g     = lane >> 1;                  // node sub-index 0..31
    const int c     = lane & 1;                   // channel half 0..1
    const int node  = chunk * 160 + wid * 32 + g; // 625*160 = 100000 exactly

    const int p0  = ptr[node];
    const int deg = ptr[node + 1] - p0;
    const int Em1 = E - 1;
    const float w = inv_deg[node];

    // preload edge indices: lane c holds edges {c, c+2, ..., c+30} of node g
    int r[16];
#pragma unroll
    for (int j = 0; j < 16; ++j) {
        int a = p0 + c + 2 * j;
        a = a < Em1 ? a : Em1;
        r[j] = idx[a];
    }

    // per-edge byte offsets into this slice (zero row for e >= deg)
    int voff[32];
#pragma unroll
    for (int e = 0; e < 32; ++e) {
        int s = __shfl(r[e >> 1], (lane & 62) | (e & 1));
        s = e < deg ? s : NODES;                  // zero row
        voff[e] = (s << 5) | (c << 4);
    }

    // SRSRC for this slice (stride=0 raw buffer)
    unsigned long long base =
        (unsigned long long)(h_s + (long)slice * (SROW * SLICE_CH));
    u32x4 srd;
    srd[0] = (unsigned int)base;
    srd[1] = (unsigned int)(base >> 32);
    srd[2] = SROW * 32;                           // num_records (bytes)
    srd[3] = 0x00020000u;

    // force w (and all compiler loads) resident before our counted gathers
    asm volatile("" :: "v"(w));

    float acc[8];
#pragma unroll
    for (int t = 0; t < 8; ++t) acc[t] = 0.0f;

    u32x4 b0[8], b1[8];
#define GATHER8(B, EBASE) \
    { _Pragma("unroll") for (int j = 0; j < 8; ++j) \
        asm volatile("buffer_load_dwordx4 %0, %1, %2, 0 offen sc0" \
                     : "=v"(B[j]) : "v"(voff[(EBASE) + j]), "s"(srd)); }
#define WAITV(N) \
    asm volatile("s_waitcnt vmcnt(" #N ")" ::: "memory"); \
    __builtin_amdgcn_sched_barrier(0);
#define ACCUM8(B) \
    { _Pragma("unroll") for (int j = 0; j < 8; ++j) { \
        acc[0] += lo2f(B[j][0]); acc[1] += hi2f(B[j][0]); \
        acc[2] += lo2f(B[j][1]); acc[3] += hi2f(B[j][1]); \
        acc[4] += lo2f(B[j][2]); acc[5] += hi2f(B[j][2]); \
        acc[6] += lo2f(B[j][3]); acc[7] += hi2f(B[j][3]); } }

    GATHER8(b0, 0);
    GATHER8(b1, 8);
    WAITV(8); ACCUM8(b0);
    GATHER8(b0, 16);
    WAITV(8); ACCUM8(b1);
    GATHER8(b1, 24);
    WAITV(8); ACCUM8(b0);
    WAITV(0); ACCUM8(b1);

    float* op = out + (long)node * DOUT + slice * SLICE_CH + c * 8;
    f32x4 o0, o1;
    o0[0] = acc[0] * w; o0[1] = acc[1] * w; o0[2] = acc[2] * w; o0[3] = acc[3] * w;
    o1[0] = acc[4] * w; o1[1] = acc[5] * w; o1[2] = acc[6] * w; o1[3] = acc[7] * w;
    *reinterpret_cast<f32x4*>(op) = o0;
    *reinterpret_cast<f32x4*>(op + 4) = o1;
}

extern "C" void kernel_launch(void* const* d_in, const int* in_sizes, int n_in,
                              void* d_out, int out_size, void* d_ws, size_t ws_size,
                              hipStream_t stream) {
    const float* x   = (const float*)d_in[0];
    const float* W   = (const float*)d_in[1];
    const int*   ptr = (const int*)d_in[2];
    const int*   idx = (const int*)d_in[3];
    // d_in[4] (dst) unused: CSR ptr encodes destinations.
    float* out = (float*)d_out;
    const int E = in_sizes[3];

    char* ws = (char*)d_ws;
    unsigned short* wsW     = (unsigned short*)ws;               // 64 KB
    float*          inv_deg = (float*)(ws + (64 << 10));         // 400 KB
    unsigned short* h_s     = (unsigned short*)(ws + (1 << 20)); // 8*SROW*16*2B

    gcn_prep<<<391, 256, 0, stream>>>(W, ptr, wsW, inv_deg, h_s);
    // ceil(100000/32) = 3125 waves -> 782 blocks x 4 waves
    gcn_gemm<<<782, 256, 0, stream>>>(x, wsW, h_s);
    // 625 chunks (160 nodes = 5 waves/block) x 8 slices; slice = blockIdx % 8
    gcn_agg<<<5000, 320, 0, stream>>>(ptr, idx, h_s, inv_deg, out, E);
}

// Round 6
// 136.355 us; speedup vs baseline: 1.0680x; 1.0680x over previous
//
#include <hip/hip_runtime.h>
#include <hip/hip_bf16.h>

typedef __attribute__((ext_vector_type(4))) float f32x4;
typedef __attribute__((ext_vector_type(8))) short s16x8;
typedef __attribute__((ext_vector_type(4))) unsigned int u32x4;

#define NODES 100000
#define SROW (NODES + 1)   // +1 zero row per slice: predication-free gathers
#define DIN 256
#define DOUT 128
#define NSLICE 4
#define SLICE_CH 32        // h_s[slice][SROW][32] bf16 = 6.4 MB/slice, 64B rows

static __device__ inline unsigned short f2bf(float f) {
    __hip_bfloat16 h = __float2bfloat16(f);
    return __builtin_bit_cast(unsigned short, h);
}
static __device__ inline float lo2f(unsigned int v) {  // low bf16 -> f32
    return __builtin_bit_cast(float, v << 16);
}
static __device__ inline float hi2f(unsigned int v) {  // high bf16 -> f32
    return __builtin_bit_cast(float, v & 0xffff0000u);
}

// ---------------- prep: W fp32 -> bf16 ; inv_deg ; zero rows ----------------
__global__ __launch_bounds__(256) void gcn_prep(const float* __restrict__ W,
                                                const int* __restrict__ ptr,
                                                unsigned short* __restrict__ wsW,
                                                float* __restrict__ inv_deg,
                                                unsigned short* __restrict__ h_s) {
    int t = blockIdx.x * 256 + threadIdx.x;
    if (t < DOUT * DIN) wsW[t] = f2bf(W[t]);
    if (t < NODES) {
        int d = ptr[t + 1] - ptr[t];
        inv_deg[t] = d > 0 ? 1.0f / (float)d : 0.0f;
    }
    if (t < NSLICE * SLICE_CH)  // zero row (node index NODES) of each slice
        h_s[(long)(t >> 5) * (SROW * SLICE_CH) + (long)NODES * SLICE_CH + (t & 31)] = 0;
}

// ---------------- GEMM: h_s[slice][SROW][32] (bf16) = x @ W.T ---------------
// 16 rows per wave -> 6252 waves (~6/SIMD) so the ~900cyc HBM latency on the
// A stream is hidden by wave-level overlap (R3/R4's 3/SIMD was the GEMM
// bottleneck, not B). Depth-1 A prefetch; B (64KB, L2-hot) compiler-scheduled.
// MFMA 16x16x32 bf16; C/D: col=lane&15, row=(lane>>4)*4+reg.
// Output col block n (16 cols) -> slice n>>1, channel (n&1)*16+lr.
__global__ __launch_bounds__(256) void gcn_gemm(const float* __restrict__ x,
                                                const unsigned short* __restrict__ wsW,
                                                unsigned short* __restrict__ h_s) {
    const int lane = threadIdx.x & 63;
    const int wid  = threadIdx.x >> 6;
    const int gwid = blockIdx.x * 4 + wid;
    const int row0 = gwid * 16;
    if (row0 >= NODES) return;
    const int lr = lane & 15;
    const int lg = lane >> 4;

    int r0 = row0 + lr;
    r0 = r0 < NODES ? r0 : NODES - 1;  // clamp; garbage rows never stored
    const float* xp = x + (long)r0 * DIN + lg * 8;

    f32x4 acc[8];
#pragma unroll
    for (int n = 0; n < 8; ++n) acc[n] = (f32x4)(0.0f);

    f32x4 c0 = *reinterpret_cast<const f32x4*>(xp);
    f32x4 c1 = *reinterpret_cast<const f32x4*>(xp + 4);

#pragma unroll
    for (int ks = 0; ks < 8; ++ks) {
        f32x4 n0, n1;
        if (ks < 7) {  // prefetch next k-step while this one computes
            n0 = *reinterpret_cast<const f32x4*>(xp + (ks + 1) * 32);
            n1 = *reinterpret_cast<const f32x4*>(xp + (ks + 1) * 32 + 4);
        } else { n0 = c0; n1 = c1; }

        s16x8 bf[8];
#pragma unroll
        for (int n = 0; n < 8; ++n)
            bf[n] = *reinterpret_cast<const s16x8*>(wsW + (n * 16 + lr) * DIN + ks * 32 + lg * 8);

        s16x8 a;
        a[0] = (short)f2bf(c0[0]); a[1] = (short)f2bf(c0[1]);
        a[2] = (short)f2bf(c0[2]); a[3] = (short)f2bf(c0[3]);
        a[4] = (short)f2bf(c1[0]); a[5] = (short)f2bf(c1[1]);
        a[6] = (short)f2bf(c1[2]); a[7] = (short)f2bf(c1[3]);

#pragma unroll
        for (int n = 0; n < 8; ++n)
            acc[n] = __builtin_amdgcn_mfma_f32_16x16x32_bf16(a, bf[n], acc[n], 0, 0, 0);

        c0 = n0; c1 = n1;
    }

#pragma unroll
    for (int n = 0; n < 8; ++n) {
        const long sb = (long)(n >> 1) * (SROW * SLICE_CH);
        const int ch = (n & 1) * 16 + lr;
#pragma unroll
        for (int r = 0; r < 4; ++r) {
            const int row = row0 + lg * 4 + r;
            if (row < NODES)
                h_s[sb + (long)row * SLICE_CH + ch] = f2bf(acc[n][r]);
        }
    }
}

// ---------------- Aggregation: 4 slices x 32ch, XCD-pair affine -------------
// Transaction-floor theory (R3==R4 at equal transaction count): 8x16ch rows
// (32B) half-used each 64B sector -> 12.8M transactions. Here rows are 64B
// (32ch), fully used -> E*4 = 6.4M transactions. Slice (6.4MB) is served by
// an XCD PAIR: XCD q = blockIdx&7 handles slice q>>1; chunk parity = q&1.
// Wave = 16 nodes; lane = (g=lane>>2: node, c=lane&3: 16B quarter-row).
// idx preloaded (r[8]); zero-row clamp -> all 32 gathers unconditional and
// independent; compiler software-pipelines them. Register-lean (R4's 23%
// occupancy came from the fat hand pipeline).
__global__ __launch_bounds__(320) void gcn_agg(const int* __restrict__ ptr,
                                               const int* __restrict__ idx,
                                               const unsigned short* __restrict__ h_s,
                                               const float* __restrict__ inv_deg,
                                               float* __restrict__ out, int E) {
    const int lane  = threadIdx.x & 63;
    const int wid   = threadIdx.x >> 6;               // 0..4
    const int slice = (blockIdx.x >> 1) & 3;          // XCD pair -> one slice
    const int chunk = (blockIdx.x >> 3) * 2 + (blockIdx.x & 1);  // 0..1249
    const int g     = lane >> 2;                      // node sub-index 0..15
    const int c     = lane & 3;                       // quarter-row 0..3
    const int node  = chunk * 80 + wid * 16 + g;      // 1250*80 = 100000

    const int p0  = ptr[node];
    const int deg = ptr[node + 1] - p0;
    const int Em1 = E - 1;
    const float w = inv_deg[node];

    // preload edge indices: lane c holds edges {c, c+4, ..., c+28} of node g
    int r[8];
#pragma unroll
    for (int j = 0; j < 8; ++j) {
        int a = p0 + c + 4 * j;
        a = a < Em1 ? a : Em1;
        r[j] = idx[a];
    }

    const unsigned short* hb = h_s + (long)slice * (SROW * SLICE_CH) + c * 8;

    float acc[8];
#pragma unroll
    for (int t = 0; t < 8; ++t) acc[t] = 0.0f;

#pragma unroll
    for (int e = 0; e < 32; ++e) {
        // edge e of node g is held by lane g*4 + (e&3), register e>>2
        int s = __shfl(r[e >> 2], (lane & 60) | (e & 3));
        s = e < deg ? s : NODES;                      // zero row: no predication
        const u32x4 v = *reinterpret_cast<const u32x4*>(hb + (long)s * SLICE_CH);
        acc[0] += lo2f(v[0]); acc[1] += hi2f(v[0]);
        acc[2] += lo2f(v[1]); acc[3] += hi2f(v[1]);
        acc[4] += lo2f(v[2]); acc[5] += hi2f(v[2]);
        acc[6] += lo2f(v[3]); acc[7] += hi2f(v[3]);
    }

    float* op = out + (long)node * DOUT + slice * SLICE_CH + c * 8;
    f32x4 o0, o1;
    o0[0] = acc[0] * w; o0[1] = acc[1] * w; o0[2] = acc[2] * w; o0[3] = acc[3] * w;
    o1[0] = acc[4] * w; o1[1] = acc[5] * w; o1[2] = acc[6] * w; o1[3] = acc[7] * w;
    *reinterpret_cast<f32x4*>(op) = o0;
    *reinterpret_cast<f32x4*>(op + 4) = o1;
}

extern "C" void kernel_launch(void* const* d_in, const int* in_sizes, int n_in,
                              void* d_out, int out_size, void* d_ws, size_t ws_size,
                              hipStream_t stream) {
    const float* x   = (const float*)d_in[0];
    const float* W   = (const float*)d_in[1];
    const int*   ptr = (const int*)d_in[2];
    const int*   idx = (const int*)d_in[3];
    // d_in[4] (dst) unused: CSR ptr encodes destinations.
    float* out = (float*)d_out;
    const int E = in_sizes[3];

    char* ws = (char*)d_ws;
    unsigned short* wsW     = (unsigned short*)ws;               // 64 KB
    float*          inv_deg = (float*)(ws + (64 << 10));         // 400 KB
    unsigned short* h_s     = (unsigned short*)(ws + (1 << 20)); // 4*SROW*32*2B

    gcn_prep<<<391, 256, 0, stream>>>(W, ptr, wsW, inv_deg, h_s);
    // ceil(100000/16) = 6250 waves -> 1563 blocks x 4 waves (~6/SIMD)
    gcn_gemm<<<1563, 256, 0, stream>>>(x, wsW, h_s);
    // 625 x 8 blocks: XCD q=blockIdx&7 -> slice q>>1, chunk=(blockIdx>>3)*2+(q&1)
    gcn_agg<<<5000, 320, 0, stream>>>(ptr, idx, h_s, inv_deg, out, E);
}

// Round 7
// 119.923 us; speedup vs baseline: 1.2144x; 1.1370x over previous
//
#include <hip/hip_runtime.h>
#include <hip/hip_bf16.h>

typedef __attribute__((ext_vector_type(4))) float f32x4;
typedef __attribute__((ext_vector_type(8))) short s16x8;
typedef __attribute__((ext_vector_type(4))) unsigned int u32x4;

#define NODES 100000
#define SROW (NODES + 1)   // +1 zero row per slice: predication-free gathers
#define DIN 256
#define DOUT 128
#define NSLICE 4
#define SLICE_CH 32        // h_s[slice][SROW][32] bf16 = 6.4 MB/slice, 64B rows

static __device__ inline unsigned short f2bf(float f) {
    __hip_bfloat16 h = __float2bfloat16(f);
    return __builtin_bit_cast(unsigned short, h);
}
static __device__ inline float lo2f(unsigned int v) {  // low bf16 -> f32
    return __builtin_bit_cast(float, v << 16);
}
static __device__ inline float hi2f(unsigned int v) {  // high bf16 -> f32
    return __builtin_bit_cast(float, v & 0xffff0000u);
}

// ---------------- prep: W fp32 -> bf16 ; inv_deg ; zero rows ----------------
__global__ __launch_bounds__(256) void gcn_prep(const float* __restrict__ W,
                                                const int* __restrict__ ptr,
                                                unsigned short* __restrict__ wsW,
                                                float* __restrict__ inv_deg,
                                                unsigned short* __restrict__ h_s) {
    int t = blockIdx.x * 256 + threadIdx.x;
    if (t < DOUT * DIN) wsW[t] = f2bf(W[t]);
    if (t < NODES) {
        int d = ptr[t + 1] - ptr[t];
        inv_deg[t] = d > 0 ? 1.0f / (float)d : 0.0f;
    }
    if (t < NSLICE * SLICE_CH)  // zero row (node index NODES) of each slice
        h_s[(long)(t >> 5) * (SROW * SLICE_CH) + (long)NODES * SLICE_CH + (t & 31)] = 0;
}

// ---------------- GEMM: h_s[slice][SROW][32] (bf16) = x @ W.T ---------------
// EXACT R1 structure (measured ~15-22us by subtraction): one wave per 32x128
// tile, acc[2][8], runtime k-loop, depth-1 A prefetch, compiler-scheduled B.
// R5's 16-row variant regressed 4x (MfmaUtil 3%, VALU 4%: 56-VGPR serialized
// load->wait chains); 32-row keeps 2 A-rows of ILP and half the B-load
// instruction count per FLOP. Only the epilogue differs from R1: write the
// 4-slice layout. MFMA 16x16x32 bf16; C/D: col=lane&15, row=(lane>>4)*4+reg.
__global__ __launch_bounds__(256) void gcn_gemm(const float* __restrict__ x,
                                                const unsigned short* __restrict__ wsW,
                                                unsigned short* __restrict__ h_s) {
    const int lane = threadIdx.x & 63;
    const int wid  = threadIdx.x >> 6;
    const int gwid = blockIdx.x * 4 + wid;
    const int row0 = gwid * 32;
    if (row0 >= NODES) return;
    const int lr = lane & 15;
    const int lg = lane >> 4;

    int r0 = row0 + lr;
    int r1 = row0 + 16 + lr;
    r0 = r0 < NODES ? r0 : NODES - 1;  // clamp; garbage rows never stored
    r1 = r1 < NODES ? r1 : NODES - 1;
    const float* xp0 = x + (long)r0 * DIN + lg * 8;
    const float* xp1 = x + (long)r1 * DIN + lg * 8;

    f32x4 acc[2][8];
#pragma unroll
    for (int m = 0; m < 2; ++m)
#pragma unroll
        for (int n = 0; n < 8; ++n) acc[m][n] = (f32x4)(0.0f);

    f32x4 c00 = *reinterpret_cast<const f32x4*>(xp0);
    f32x4 c01 = *reinterpret_cast<const f32x4*>(xp0 + 4);
    f32x4 c10 = *reinterpret_cast<const f32x4*>(xp1);
    f32x4 c11 = *reinterpret_cast<const f32x4*>(xp1 + 4);

    for (int ks = 0; ks < 8; ++ks) {
        const int kk = ks * 32 + lg * 8;
        s16x8 bf[8];
#pragma unroll
        for (int n = 0; n < 8; ++n)
            bf[n] = *reinterpret_cast<const s16x8*>(wsW + (n * 16 + lr) * DIN + kk);

        f32x4 n00, n01, n10, n11;
        if (ks < 7) {  // prefetch next k-step while MFMAs run
            n00 = *reinterpret_cast<const f32x4*>(xp0 + (ks + 1) * 32);
            n01 = *reinterpret_cast<const f32x4*>(xp0 + (ks + 1) * 32 + 4);
            n10 = *reinterpret_cast<const f32x4*>(xp1 + (ks + 1) * 32);
            n11 = *reinterpret_cast<const f32x4*>(xp1 + (ks + 1) * 32 + 4);
        } else {
            n00 = c00; n01 = c01; n10 = c10; n11 = c11;
        }

        s16x8 a0, a1;
        a0[0] = (short)f2bf(c00[0]); a0[1] = (short)f2bf(c00[1]);
        a0[2] = (short)f2bf(c00[2]); a0[3] = (short)f2bf(c00[3]);
        a0[4] = (short)f2bf(c01[0]); a0[5] = (short)f2bf(c01[1]);
        a0[6] = (short)f2bf(c01[2]); a0[7] = (short)f2bf(c01[3]);
        a1[0] = (short)f2bf(c10[0]); a1[1] = (short)f2bf(c10[1]);
        a1[2] = (short)f2bf(c10[2]); a1[3] = (short)f2bf(c10[3]);
        a1[4] = (short)f2bf(c11[0]); a1[5] = (short)f2bf(c11[1]);
        a1[6] = (short)f2bf(c11[2]); a1[7] = (short)f2bf(c11[3]);

#pragma unroll
        for (int n = 0; n < 8; ++n) {
            acc[0][n] = __builtin_amdgcn_mfma_f32_16x16x32_bf16(a0, bf[n], acc[0][n], 0, 0, 0);
            acc[1][n] = __builtin_amdgcn_mfma_f32_16x16x32_bf16(a1, bf[n], acc[1][n], 0, 0, 0);
        }
        c00 = n00; c01 = n01; c10 = n10; c11 = n11;
    }

#pragma unroll
    for (int m = 0; m < 2; ++m) {
        const int rbase = row0 + m * 16 + lg * 4;
#pragma unroll
        for (int n = 0; n < 8; ++n) {
            const long sb = (long)(n >> 1) * (SROW * SLICE_CH);
            const int ch = (n & 1) * 16 + lr;
#pragma unroll
            for (int r = 0; r < 4; ++r) {
                const int row = rbase + r;
                if (row < NODES)
                    h_s[sb + (long)row * SLICE_CH + ch] = f2bf(acc[m][n][r]);
            }
        }
    }
}

// ---------------- Aggregation: 4 slices x 32ch, XCD-pair affine -------------
// (unchanged from R5 — measured ~45us by subtraction, 2x better than R4,
// confirming the transaction-count model: E*4 fully-used 64B rows.)
// Slice (6.4MB) served by an XCD PAIR: XCD q = blockIdx&7 -> slice q>>1,
// chunk parity q&1. Wave = 16 nodes; lane = (g=lane>>2: node, c=lane&3:
// 16B quarter-row). idx preloaded (r[8]); zero-row clamp -> all 32 gathers
// unconditional; compiler software-pipelines them.
__global__ __launch_bounds__(320) void gcn_agg(const int* __restrict__ ptr,
                                               const int* __restrict__ idx,
                                               const unsigned short* __restrict__ h_s,
                                               const float* __restrict__ inv_deg,
                                               float* __restrict__ out, int E) {
    const int lane  = threadIdx.x & 63;
    const int wid   = threadIdx.x >> 6;               // 0..4
    const int slice = (blockIdx.x >> 1) & 3;          // XCD pair -> one slice
    const int chunk = (blockIdx.x >> 3) * 2 + (blockIdx.x & 1);  // 0..1249
    const int g     = lane >> 2;                      // node sub-index 0..15
    const int c     = lane & 3;                       // quarter-row 0..3
    const int node  = chunk * 80 + wid * 16 + g;      // 1250*80 = 100000

    const int p0  = ptr[node];
    const int deg = ptr[node + 1] - p0;
    const int Em1 = E - 1;
    const float w = inv_deg[node];

    // preload edge indices: lane c holds edges {c, c+4, ..., c+28} of node g
    int r[8];
#pragma unroll
    for (int j = 0; j < 8; ++j) {
        int a = p0 + c + 4 * j;
        a = a < Em1 ? a : Em1;
        r[j] = idx[a];
    }

    const unsigned short* hb = h_s + (long)slice * (SROW * SLICE_CH) + c * 8;

    float acc[8];
#pragma unroll
    for (int t = 0; t < 8; ++t) acc[t] = 0.0f;

#pragma unroll
    for (int e = 0; e < 32; ++e) {
        // edge e of node g is held by lane g*4 + (e&3), register e>>2
        int s = __shfl(r[e >> 2], (lane & 60) | (e & 3));
        s = e < deg ? s : NODES;                      // zero row: no predication
        const u32x4 v = *reinterpret_cast<const u32x4*>(hb + (long)s * SLICE_CH);
        acc[0] += lo2f(v[0]); acc[1] += hi2f(v[0]);
        acc[2] += lo2f(v[1]); acc[3] += hi2f(v[1]);
        acc[4] += lo2f(v[2]); acc[5] += hi2f(v[2]);
        acc[6] += lo2f(v[3]); acc[7] += hi2f(v[3]);
    }

    float* op = out + (long)node * DOUT + slice * SLICE_CH + c * 8;
    f32x4 o0, o1;
    o0[0] = acc[0] * w; o0[1] = acc[1] * w; o0[2] = acc[2] * w; o0[3] = acc[3] * w;
    o1[0] = acc[4] * w; o1[1] = acc[5] * w; o1[2] = acc[6] * w; o1[3] = acc[7] * w;
    *reinterpret_cast<f32x4*>(op) = o0;
    *reinterpret_cast<f32x4*>(op + 4) = o1;
}

extern "C" void kernel_launch(void* const* d_in, const int* in_sizes, int n_in,
                              void* d_out, int out_size, void* d_ws, size_t ws_size,
                              hipStream_t stream) {
    const float* x   = (const float*)d_in[0];
    const float* W   = (const float*)d_in[1];
    const int*   ptr = (const int*)d_in[2];
    const int*   idx = (const int*)d_in[3];
    // d_in[4] (dst) unused: CSR ptr encodes destinations.
    float* out = (float*)d_out;
    const int E = in_sizes[3];

    char* ws = (char*)d_ws;
    unsigned short* wsW     = (unsigned short*)ws;               // 64 KB
    float*          inv_deg = (float*)(ws + (64 << 10));         // 400 KB
    unsigned short* h_s     = (unsigned short*)(ws + (1 << 20)); // 4*SROW*32*2B

    gcn_prep<<<391, 256, 0, stream>>>(W, ptr, wsW, inv_deg, h_s);
    // ceil(100000/32) = 3125 waves -> 782 blocks x 4 waves
    gcn_gemm<<<782, 256, 0, stream>>>(x, wsW, h_s);
    // 625 x 8 blocks: XCD q=blockIdx&7 -> slice q>>1, chunk=(blockIdx>>3)*2+(q&1)
    gcn_agg<<<5000, 320, 0, stream>>>(ptr, idx, h_s, inv_deg, out, E);
}

// Round 8
// 115.737 us; speedup vs baseline: 1.2583x; 1.0362x over previous
//
#include <hip/hip_runtime.h>
#include <hip/hip_bf16.h>

typedef __attribute__((ext_vector_type(4))) float f32x4;
typedef __attribute__((ext_vector_type(8))) short s16x8;
typedef __attribute__((ext_vector_type(4))) unsigned int u32x4;

#define NODES 100000
#define SROW (NODES + 1)   // +1 zero row per slice: predication-free gathers
#define DIN 256
#define DOUT 128
#define NSLICE 2
#define SLICE_CH 64        // h_s[slice][SROW][64] bf16 = 12.8 MB/slice, 128B rows

static __device__ inline unsigned short f2bf(float f) {
    __hip_bfloat16 h = __float2bfloat16(f);
    return __builtin_bit_cast(unsigned short, h);
}
static __device__ inline float lo2f(unsigned int v) {  // low bf16 -> f32
    return __builtin_bit_cast(float, v << 16);
}
static __device__ inline float hi2f(unsigned int v) {  // high bf16 -> f32
    return __builtin_bit_cast(float, v & 0xffff0000u);
}

// ---------------- prep: W fp32 -> bf16 ; inv_deg ; zero rows ----------------
__global__ __launch_bounds__(256) void gcn_prep(const float* __restrict__ W,
                                                const int* __restrict__ ptr,
                                                unsigned short* __restrict__ wsW,
                                                float* __restrict__ inv_deg,
                                                unsigned short* __restrict__ h_s) {
    int t = blockIdx.x * 256 + threadIdx.x;
    if (t < DOUT * DIN) wsW[t] = f2bf(W[t]);
    if (t < NODES) {
        int d = ptr[t + 1] - ptr[t];
        inv_deg[t] = d > 0 ? 1.0f / (float)d : 0.0f;
    }
    if (t < NSLICE * SLICE_CH)  // zero row (node index NODES) of each slice
        h_s[(long)(t >> 6) * ((long)SROW * SLICE_CH) + (long)NODES * SLICE_CH + (t & 63)] = 0;
}

// ---------------- GEMM: h_s[slice][SROW][64] (bf16) = x @ W.T ---------------
// R7 diagnosis: 70us at MfmaUtil 3%, VALU 9%, occ 22% -> exposed-latency bound
// (depth-1 prefetch = 2KB in flight/wave; need ~9.4KB/CU chip-wide).
// Fix: issue ALL 32 A dwordx4 loads upfront (256B/lane = 16KB/wave in flight,
// pinned by sched_barrier), convert to bf16 in arrival order (frees raw regs),
// then 8 MFMA steps against L2-hot B. launch_bounds(256,2) caps VGPR at 256.
// MFMA 16x16x32 bf16; C/D: col=lane&15, row=(lane>>4)*4+reg.
// Output col block n (16 cols) -> slice n>>2, channel (n&3)*16+lr.
__global__ __launch_bounds__(256, 2) void gcn_gemm(const float* __restrict__ x,
                                                   const unsigned short* __restrict__ wsW,
                                                   unsigned short* __restrict__ h_s) {
    const int lane = threadIdx.x & 63;
    const int wid  = threadIdx.x >> 6;
    const int gwid = blockIdx.x * 4 + wid;
    const int row0 = gwid * 32;
    if (row0 >= NODES) return;
    const int lr = lane & 15;
    const int lg = lane >> 4;

    int r0 = row0 + lr;
    int r1 = row0 + 16 + lr;
    r0 = r0 < NODES ? r0 : NODES - 1;  // clamp; garbage rows never stored
    r1 = r1 < NODES ? r1 : NODES - 1;
    const float* xp0 = x + (long)r0 * DIN + lg * 8;
    const float* xp1 = x + (long)r1 * DIN + lg * 8;

    // Phase 1: issue ALL A loads (32 x dwordx4). Two base addrs, imm offsets.
    f32x4 araw[2][8][2];
#pragma unroll
    for (int ks = 0; ks < 8; ++ks) {
        araw[0][ks][0] = *reinterpret_cast<const f32x4*>(xp0 + ks * 32);
        araw[0][ks][1] = *reinterpret_cast<const f32x4*>(xp0 + ks * 32 + 4);
        araw[1][ks][0] = *reinterpret_cast<const f32x4*>(xp1 + ks * 32);
        araw[1][ks][1] = *reinterpret_cast<const f32x4*>(xp1 + ks * 32 + 4);
    }
    __builtin_amdgcn_sched_barrier(0);  // pin: all loads issued before anything sinks

    // Phase 2: convert to bf16 in arrival order (in-order vmcnt completion:
    // waiting on load k implies 0..k-1 done; araw regs die progressively).
    s16x8 abf[2][8];
#pragma unroll
    for (int ks = 0; ks < 8; ++ks) {
#pragma unroll
        for (int m = 0; m < 2; ++m) {
            s16x8 a;
            a[0] = (short)f2bf(araw[m][ks][0][0]); a[1] = (short)f2bf(araw[m][ks][0][1]);
            a[2] = (short)f2bf(araw[m][ks][0][2]); a[3] = (short)f2bf(araw[m][ks][0][3]);
            a[4] = (short)f2bf(araw[m][ks][1][0]); a[5] = (short)f2bf(araw[m][ks][1][1]);
            a[6] = (short)f2bf(araw[m][ks][1][2]); a[7] = (short)f2bf(araw[m][ks][1][3]);
            abf[m][ks] = a;
        }
    }

    // Phase 3: MFMA against L2-hot B (64 KB table).
    f32x4 acc[2][8];
#pragma unroll
    for (int m = 0; m < 2; ++m)
#pragma unroll
        for (int n = 0; n < 8; ++n) acc[m][n] = (f32x4)(0.0f);

#pragma unroll
    for (int ks = 0; ks < 8; ++ks) {
        const int kk = ks * 32 + lg * 8;
        s16x8 bf[8];
#pragma unroll
        for (int n = 0; n < 8; ++n)
            bf[n] = *reinterpret_cast<const s16x8*>(wsW + (n * 16 + lr) * DIN + kk);
#pragma unroll
        for (int n = 0; n < 8; ++n) {
            acc[0][n] = __builtin_amdgcn_mfma_f32_16x16x32_bf16(abf[0][ks], bf[n], acc[0][n], 0, 0, 0);
            acc[1][n] = __builtin_amdgcn_mfma_f32_16x16x32_bf16(abf[1][ks], bf[n], acc[1][n], 0, 0, 0);
        }
    }

#pragma unroll
    for (int m = 0; m < 2; ++m) {
        const int rbase = row0 + m * 16 + lg * 4;
#pragma unroll
        for (int n = 0; n < 8; ++n) {
            const long sb = (long)(n >> 2) * ((long)SROW * SLICE_CH);
            const int ch = (n & 3) * 16 + lr;
#pragma unroll
            for (int r = 0; r < 4; ++r) {
                const int row = rbase + r;
                if (row < NODES)
                    h_s[sb + (long)row * SLICE_CH + ch] = f2bf(acc[m][n][r]);
            }
        }
    }
}

// ---------------- Aggregation: 2 slices x 64ch, XCD-quad affine -------------
// R4->R5 established cost ∝ row-accesses/edge (8 -> 4 halved time). Here rows
// are 128B (64ch): accesses/edge = 2 under 128B-line granularity (predict
// ~25us), = 4 under 64B-sector granularity (predict flat ~45us -> learn the
// bf16 floor). Slice (12.8MB) served by XCD QUAD: q = blockIdx&7 -> slice
// q>>2, chunk sub-index q&3. Wave = 8 nodes; lane = (g=lane>>3: node,
// c=lane&7: 16B eighth-row). idx preloaded (r[4]); zero-row clamp -> all 32
// gathers unconditional; compiler software-pipelines them.
__global__ __launch_bounds__(320) void gcn_agg(const int* __restrict__ ptr,
                                               const int* __restrict__ idx,
                                               const unsigned short* __restrict__ h_s,
                                               const float* __restrict__ inv_deg,
                                               float* __restrict__ out, int E) {
    const int lane  = threadIdx.x & 63;
    const int wid   = threadIdx.x >> 6;               // 0..4
    const int q     = blockIdx.x & 7;                 // XCD id
    const int slice = q >> 2;                         // 0..1
    const int chunk = (blockIdx.x >> 3) * 4 + (q & 3);  // 0..2499
    const int g     = lane >> 3;                      // node sub-index 0..7
    const int c     = lane & 7;                       // eighth-row 0..7
    const int node  = chunk * 40 + wid * 8 + g;       // 2500*40 = 100000

    const int p0  = ptr[node];
    const int deg = ptr[node + 1] - p0;
    const int Em1 = E - 1;
    const float w = inv_deg[node];

    // preload edge indices: lane c holds edges {c, c+8, c+16, c+24} of node g
    int r[4];
#pragma unroll
    for (int j = 0; j < 4; ++j) {
        int a = p0 + c + 8 * j;
        a = a < Em1 ? a : Em1;
        r[j] = idx[a];
    }

    const unsigned short* hb = h_s + (long)slice * ((long)SROW * SLICE_CH) + c * 8;

    float acc[8];
#pragma unroll
    for (int t = 0; t < 8; ++t) acc[t] = 0.0f;

#pragma unroll
    for (int e = 0; e < 32; ++e) {
        // edge e of node g is held by lane g*8 + (e&7), register e>>3
        int s = __shfl(r[e >> 3], (lane & 56) | (e & 7));
        s = e < deg ? s : NODES;                      // zero row: no predication
        const u32x4 v = *reinterpret_cast<const u32x4*>(hb + (long)s * SLICE_CH);
        acc[0] += lo2f(v[0]); acc[1] += hi2f(v[0]);
        acc[2] += lo2f(v[1]); acc[3] += hi2f(v[1]);
        acc[4] += lo2f(v[2]); acc[5] += hi2f(v[2]);
        acc[6] += lo2f(v[3]); acc[7] += hi2f(v[3]);
    }

    float* op = out + (long)node * DOUT + slice * SLICE_CH + c * 8;
    f32x4 o0, o1;
    o0[0] = acc[0] * w; o0[1] = acc[1] * w; o0[2] = acc[2] * w; o0[3] = acc[3] * w;
    o1[0] = acc[4] * w; o1[1] = acc[5] * w; o1[2] = acc[6] * w; o1[3] = acc[7] * w;
    *reinterpret_cast<f32x4*>(op) = o0;
    *reinterpret_cast<f32x4*>(op + 4) = o1;
}

extern "C" void kernel_launch(void* const* d_in, const int* in_sizes, int n_in,
                              void* d_out, int out_size, void* d_ws, size_t ws_size,
                              hipStream_t stream) {
    const float* x   = (const float*)d_in[0];
    const float* W   = (const float*)d_in[1];
    const int*   ptr = (const int*)d_in[2];
    const int*   idx = (const int*)d_in[3];
    // d_in[4] (dst) unused: CSR ptr encodes destinations.
    float* out = (float*)d_out;
    const int E = in_sizes[3];

    char* ws = (char*)d_ws;
    unsigned short* wsW     = (unsigned short*)ws;               // 64 KB
    float*          inv_deg = (float*)(ws + (64 << 10));         // 400 KB
    unsigned short* h_s     = (unsigned short*)(ws + (1 << 20)); // 2*SROW*64*2B

    gcn_prep<<<391, 256, 0, stream>>>(W, ptr, wsW, inv_deg, h_s);
    // ceil(100000/32) = 3125 waves -> 782 blocks x 4 waves
    gcn_gemm<<<782, 256, 0, stream>>>(x, wsW, h_s);
    // 625 x 8 blocks: XCD q=blockIdx&7 -> slice q>>2, chunk=(blockIdx>>3)*4+(q&3)
    gcn_agg<<<5000, 320, 0, stream>>>(ptr, idx, h_s, inv_deg, out, E);
}

// Round 9
// 88.717 us; speedup vs baseline: 1.6415x; 1.3046x over previous
//
#include <hip/hip_runtime.h>
#include <hip/hip_bf16.h>

typedef __attribute__((ext_vector_type(4))) float f32x4;
typedef __attribute__((ext_vector_type(8))) short s16x8;
typedef __attribute__((ext_vector_type(4))) short s16x4;
typedef __attribute__((ext_vector_type(4))) unsigned int u32x4;
typedef __attribute__((ext_vector_type(2))) unsigned int u32x2;

#define NODES 100000
#define SROW (NODES + 1)   // +1 zero row per slice: predication-free gathers
#define DIN 256
#define DOUT 128
#define NSLICE 2
#define SLICE_CH 64        // h_s[slice][SROW][64] bf16 = 12.8 MB/slice

static __device__ inline unsigned short f2bf(float f) {
    __hip_bfloat16 h = __float2bfloat16(f);
    return __builtin_bit_cast(unsigned short, h);
}
static __device__ inline float lo2f(unsigned int v) {  // low bf16 -> f32
    return __builtin_bit_cast(float, v << 16);
}
static __device__ inline float hi2f(unsigned int v) {  // high bf16 -> f32
    return __builtin_bit_cast(float, v & 0xffff0000u);
}

// ---------------- prep: W fp32 -> bf16 ; inv_deg ; zero rows ----------------
__global__ __launch_bounds__(256) void gcn_prep(const float* __restrict__ W,
                                                const int* __restrict__ ptr,
                                                unsigned short* __restrict__ wsW,
                                                float* __restrict__ inv_deg,
                                                unsigned short* __restrict__ h_s) {
    int t = blockIdx.x * 256 + threadIdx.x;
    if (t < DOUT * DIN) wsW[t] = f2bf(W[t]);
    if (t < NODES) {
        int d = ptr[t + 1] - ptr[t];
        inv_deg[t] = d > 0 ? 1.0f / (float)d : 0.0f;
    }
    if (t < NSLICE * SLICE_CH)  // zero row (node index NODES) of each slice
        h_s[(long)(t >> 6) * ((long)SROW * SLICE_CH) + (long)NODES * SLICE_CH + (t & 63)] = 0;
}

// ---------------- GEMM: h_s[slice][SROW][64] (bf16) = x @ W.T ---------------
// R8 diagnosis: all direct-from-global fragment schedules stall at ~72us
// because every fragment load scatters 64 lanes across 16 rows (1KB stride,
// half-used sectors) -> ~3K sector-transactions/wave, TA-bound at 3% MFMA.
// Fix = the canonical LDS-staged GEMM (m97 ladder): block = 128x128 out tile,
// 4 waves, K-chunks of 64. Reg-stage A (coalesced 16B/lane fp32 -> cvt bf16)
// and B (8B/lane) into XOR-swizzled LDS (T2: idx = row*64 + (c4^((row&7)<<3));
// read-side conflicts drop to 2-way = free). Next chunk's global loads issue
// BEFORE the compute phase (T14) so HBM latency hides under MFMA + barrier.
// MFMA 16x16x32 bf16; C/D: col=lane&15, row=(lane>>4)*4+reg.
// Output col block n (16 cols) -> slice n>>2, channel (n&3)*16+lr.
__global__ __launch_bounds__(256) void gcn_gemm(const float* __restrict__ x,
                                                const unsigned short* __restrict__ wsW,
                                                unsigned short* __restrict__ h_s) {
    const int tid  = threadIdx.x;
    const int lane = tid & 63;
    const int wid  = tid >> 6;
    const int row0 = blockIdx.x * 128;
    const int lr = lane & 15;
    const int lg = lane >> 4;

    __shared__ unsigned short ldsA[128 * 64];  // 16 KB, swizzled [row][64k]
    __shared__ unsigned short ldsB[128 * 64];  // 16 KB, swizzled [out][64k]

    const int st_sub = tid >> 4;        // staging row sub-index 0..15
    const int st_c4  = (tid & 15) * 4;  // staging col (element*4)

    f32x4 ar[8];   // A stage regs: 8 rounds x 16B (4 fp32)
    u32x2 br[8];   // B stage regs: 8 rounds x 8B (4 bf16)

#define LOADA(C) { _Pragma("unroll") for (int j = 0; j < 8; ++j) { \
        int grow = row0 + j * 16 + st_sub; \
        grow = grow < NODES ? grow : NODES - 1; /* clamp; never stored */ \
        ar[j] = *reinterpret_cast<const f32x4*>(x + (long)grow * DIN + (C) * 64 + st_c4); } }

#define LOADB(C) { _Pragma("unroll") for (int j = 0; j < 8; ++j) { \
        const int out = j * 16 + st_sub; \
        br[j] = *reinterpret_cast<const u32x2*>(wsW + out * DIN + (C) * 64 + st_c4); } }

    // A and B share the same (row, col) staging map -> same swizzled index.
#define STAGE() { _Pragma("unroll") for (int j = 0; j < 8; ++j) { \
        const int row = j * 16 + st_sub; \
        const int idx = row * 64 + (st_c4 ^ ((row & 7) << 3)); \
        s16x4 pa; \
        pa[0] = (short)f2bf(ar[j][0]); pa[1] = (short)f2bf(ar[j][1]); \
        pa[2] = (short)f2bf(ar[j][2]); pa[3] = (short)f2bf(ar[j][3]); \
        *reinterpret_cast<s16x4*>(ldsA + idx) = pa; \
        *reinterpret_cast<u32x2*>(ldsB + idx) = br[j]; } }

#define COMPUTE() { _Pragma("unroll") for (int ks = 0; ks < 2; ++ks) { \
        s16x8 a[2], b[8]; \
        _Pragma("unroll") for (int m = 0; m < 2; ++m) { \
            const int row = wid * 32 + m * 16 + lr; \
            const int idx = row * 64 + ((ks * 32 + lg * 8) ^ ((row & 7) << 3)); \
            a[m] = *reinterpret_cast<const s16x8*>(ldsA + idx); } \
        _Pragma("unroll") for (int n = 0; n < 8; ++n) { \
            const int out = n * 16 + lr; \
            const int idx = out * 64 + ((ks * 32 + lg * 8) ^ ((out & 7) << 3)); \
            b[n] = *reinterpret_cast<const s16x8*>(ldsB + idx); } \
        _Pragma("unroll") for (int n = 0; n < 8; ++n) { \
            acc[0][n] = __builtin_amdgcn_mfma_f32_16x16x32_bf16(a[0], b[n], acc[0][n], 0, 0, 0); \
            acc[1][n] = __builtin_amdgcn_mfma_f32_16x16x32_bf16(a[1], b[n], acc[1][n], 0, 0, 0); } } }

    f32x4 acc[2][8];
#pragma unroll
    for (int m = 0; m < 2; ++m)
#pragma unroll
        for (int n = 0; n < 8; ++n) acc[m][n] = (f32x4)(0.0f);

    // chunk pipeline: loads for c+1 issued before COMPUTE(c) so HBM latency
    // hides under the LDS-only MFMA phase (T14 issue-early / write-late).
    LOADA(0); LOADB(0);
    STAGE();
    __syncthreads();
    LOADA(1); LOADB(1);
    COMPUTE();
    __syncthreads();
    STAGE();
    __syncthreads();
    LOADA(2); LOADB(2);
    COMPUTE();
    __syncthreads();
    STAGE();
    __syncthreads();
    LOADA(3); LOADB(3);
    COMPUTE();
    __syncthreads();
    STAGE();
    __syncthreads();
    COMPUTE();

#pragma unroll
    for (int m = 0; m < 2; ++m) {
        const int rbase = row0 + wid * 32 + m * 16 + lg * 4;
#pragma unroll
        for (int n = 0; n < 8; ++n) {
            const long sb = (long)(n >> 2) * ((long)SROW * SLICE_CH);
            const int ch = (n & 3) * 16 + lr;
#pragma unroll
            for (int r = 0; r < 4; ++r) {
                const int row = rbase + r;
                if (row < NODES)
                    h_s[sb + (long)row * SLICE_CH + ch] = f2bf(acc[m][n][r]);
            }
        }
    }
#undef LOADA
#undef LOADB
#undef STAGE
#undef COMPUTE
}

// ---------------- Aggregation: 2 slices x 64ch, XCD-quad affine -------------
// (unchanged from R8: ~43us by subtraction; R5(4x32) == R8(2x64) confirms the
// 64B-sector granularity floor: 4 sector-accesses per edge either way.)
// Slice (12.8MB) served by XCD QUAD: q = blockIdx&7 -> slice q>>2, chunk
// sub-index q&3. Wave = 8 nodes; lane = (g=lane>>3: node, c=lane&7: 16B
// eighth-row). idx preloaded (r[4]); zero-row clamp -> all 32 gathers
// unconditional; compiler software-pipelines them.
__global__ __launch_bounds__(320) void gcn_agg(const int* __restrict__ ptr,
                                               const int* __restrict__ idx,
                                               const unsigned short* __restrict__ h_s,
                                               const float* __restrict__ inv_deg,
                                               float* __restrict__ out, int E) {
    const int lane  = threadIdx.x & 63;
    const int wid   = threadIdx.x >> 6;               // 0..4
    const int q     = blockIdx.x & 7;                 // XCD id
    const int slice = q >> 2;                         // 0..1
    const int chunk = (blockIdx.x >> 3) * 4 + (q & 3);  // 0..2499
    const int g     = lane >> 3;                      // node sub-index 0..7
    const int c     = lane & 7;                       // eighth-row 0..7
    const int node  = chunk * 40 + wid * 8 + g;       // 2500*40 = 100000

    const int p0  = ptr[node];
    const int deg = ptr[node + 1] - p0;
    const int Em1 = E - 1;
    const float w = inv_deg[node];

    // preload edge indices: lane c holds edges {c, c+8, c+16, c+24} of node g
    int r[4];
#pragma unroll
    for (int j = 0; j < 4; ++j) {
        int a = p0 + c + 8 * j;
        a = a < Em1 ? a : Em1;
        r[j] = idx[a];
    }

    const unsigned short* hb = h_s + (long)slice * ((long)SROW * SLICE_CH) + c * 8;

    float acc[8];
#pragma unroll
    for (int t = 0; t < 8; ++t) acc[t] = 0.0f;

#pragma unroll
    for (int e = 0; e < 32; ++e) {
        // edge e of node g is held by lane g*8 + (e&7), register e>>3
        int s = __shfl(r[e >> 3], (lane & 56) | (e & 7));
        s = e < deg ? s : NODES;                      // zero row: no predication
        const u32x4 v = *reinterpret_cast<const u32x4*>(hb + (long)s * SLICE_CH);
        acc[0] += lo2f(v[0]); acc[1] += hi2f(v[0]);
        acc[2] += lo2f(v[1]); acc[3] += hi2f(v[1]);
        acc[4] += lo2f(v[2]); acc[5] += hi2f(v[2]);
        acc[6] += lo2f(v[3]); acc[7] += hi2f(v[3]);
    }

    float* op = out + (long)node * DOUT + slice * SLICE_CH + c * 8;
    f32x4 o0, o1;
    o0[0] = acc[0] * w; o0[1] = acc[1] * w; o0[2] = acc[2] * w; o0[3] = acc[3] * w;
    o1[0] = acc[4] * w; o1[1] = acc[5] * w; o1[2] = acc[6] * w; o1[3] = acc[7] * w;
    *reinterpret_cast<f32x4*>(op) = o0;
    *reinterpret_cast<f32x4*>(op + 4) = o1;
}

extern "C" void kernel_launch(void* const* d_in, const int* in_sizes, int n_in,
                              void* d_out, int out_size, void* d_ws, size_t ws_size,
                              hipStream_t stream) {
    const float* x   = (const float*)d_in[0];
    const float* W   = (const float*)d_in[1];
    const int*   ptr = (const int*)d_in[2];
    const int*   idx = (const int*)d_in[3];
    // d_in[4] (dst) unused: CSR ptr encodes destinations.
    float* out = (float*)d_out;
    const int E = in_sizes[3];

    char* ws = (char*)d_ws;
    unsigned short* wsW     = (unsigned short*)ws;               // 64 KB
    float*          inv_deg = (float*)(ws + (64 << 10));         // 400 KB
    unsigned short* h_s     = (unsigned short*)(ws + (1 << 20)); // 2*SROW*64*2B

    gcn_prep<<<391, 256, 0, stream>>>(W, ptr, wsW, inv_deg, h_s);
    // 782 blocks x (128 rows x 128 cols) tile; 4 waves/block
    gcn_gemm<<<782, 256, 0, stream>>>(x, wsW, h_s);
    // 625 x 8 blocks: XCD q=blockIdx&7 -> slice q>>2, chunk=(blockIdx>>3)*4+(q&3)
    gcn_agg<<<5000, 320, 0, stream>>>(ptr, idx, h_s, inv_deg, out, E);
}

// Round 10
// 88.085 us; speedup vs baseline: 1.6533x; 1.0072x over previous
//
#include <hip/hip_runtime.h>
#include <hip/hip_bf16.h>

typedef __attribute__((ext_vector_type(4))) float f32x4;
typedef __attribute__((ext_vector_type(8))) short s16x8;
typedef __attribute__((ext_vector_type(4))) short s16x4;
typedef __attribute__((ext_vector_type(4))) unsigned int u32x4;
typedef __attribute__((ext_vector_type(2))) unsigned int u32x2;

#define NODES 100000
#define SROW (NODES + 1)   // +1 zero row per slice: predication-free gathers
#define DIN 256
#define DOUT 128
#define NSLICE 2
#define SLICE_CH 64        // h_s[slice][SROW][64] bf16 = 12.8 MB/slice
#define EW 136             // epilogue LDS row stride (128 + 8 pad shorts)

static __device__ inline unsigned short f2bf(float f) {
    __hip_bfloat16 h = __float2bfloat16(f);
    return __builtin_bit_cast(unsigned short, h);
}
static __device__ inline float lo2f(unsigned int v) {  // low bf16 -> f32
    return __builtin_bit_cast(float, v << 16);
}
static __device__ inline float hi2f(unsigned int v) {  // high bf16 -> f32
    return __builtin_bit_cast(float, v & 0xffff0000u);
}

// ---------------- prep: W fp32 -> bf16 ; inv_deg ; zero rows ----------------
__global__ __launch_bounds__(256) void gcn_prep(const float* __restrict__ W,
                                                const int* __restrict__ ptr,
                                                unsigned short* __restrict__ wsW,
                                                float* __restrict__ inv_deg,
                                                unsigned short* __restrict__ h_s) {
    int t = blockIdx.x * 256 + threadIdx.x;
    if (t < DOUT * DIN) wsW[t] = f2bf(W[t]);
    if (t < NODES) {
        int d = ptr[t + 1] - ptr[t];
        inv_deg[t] = d > 0 ? 1.0f / (float)d : 0.0f;
    }
    if (t < NSLICE * SLICE_CH)  // zero row (node index NODES) of each slice
        h_s[(long)(t >> 6) * ((long)SROW * SLICE_CH) + (long)NODES * SLICE_CH + (t & 63)] = 0;
}

// ---------------- GEMM: h_s[slice][SROW][64] (bf16) = x @ W.T ---------------
// R9 (single-buffer LDS, 2 barriers/chunk, scalar C-write) = 45us. This round:
// (1) double-buffered LDS, ONE barrier per chunk: STAGE(c) || LOAD(c+1) ||
//     COMPUTE(c-1) -> barrier. Loads get the whole MFMA window to land.
// (2) LDS-transposed epilogue: acc -> padded [128][136] LDS tile -> row-linear
//     re-read -> 16B fully-dense global stores (8x fewer store instrs,
//     ~2x fewer write sectors than the scalar 2B scatter).
// Staging swizzle identical to R9 (T2 XOR, verified): idx = row*64 +
// (c4 ^ ((row&7)<<3)). MFMA 16x16x32; C/D: col=lane&15, row=(lane>>4)*4+reg.
__global__ __launch_bounds__(256) void gcn_gemm(const float* __restrict__ x,
                                                const unsigned short* __restrict__ wsW,
                                                unsigned short* __restrict__ h_s) {
    const int tid  = threadIdx.x;
    const int lane = tid & 63;
    const int wid  = tid >> 6;
    const int row0 = blockIdx.x * 128;
    const int lr = lane & 15;
    const int lg = lane >> 4;

    __shared__ char smem[65536];
    unsigned short* A0 = (unsigned short*)smem;          // 16 KB
    unsigned short* B0 = A0 + 8192;                      // 16 KB
    unsigned short* A1 = B0 + 8192;                      // 16 KB
    unsigned short* B1 = A1 + 8192;                      // 16 KB
    unsigned short* EP = (unsigned short*)smem;          // epilogue reuse (34.8 KB)

    const int st_sub = tid >> 4;        // staging row sub-index 0..15
    const int st_c4  = (tid & 15) * 4;  // staging col (element*4)

    f32x4 ar[8];   // A stage regs: 8 rounds x 16B (4 fp32)
    u32x2 br[8];   // B stage regs: 8 rounds x 8B (4 bf16)

#define LOADA(C) { _Pragma("unroll") for (int j = 0; j < 8; ++j) { \
        int grow = row0 + j * 16 + st_sub; \
        grow = grow < NODES ? grow : NODES - 1; /* clamp; never stored */ \
        ar[j] = *reinterpret_cast<const f32x4*>(x + (long)grow * DIN + (C) * 64 + st_c4); } }

#define LOADB(C) { _Pragma("unroll") for (int j = 0; j < 8; ++j) { \
        const int out = j * 16 + st_sub; \
        br[j] = *reinterpret_cast<const u32x2*>(wsW + out * DIN + (C) * 64 + st_c4); } }

#define STAGE(LA, LB) { _Pragma("unroll") for (int j = 0; j < 8; ++j) { \
        const int row = j * 16 + st_sub; \
        const int idx = row * 64 + (st_c4 ^ ((row & 7) << 3)); \
        s16x4 pa; \
        pa[0] = (short)f2bf(ar[j][0]); pa[1] = (short)f2bf(ar[j][1]); \
        pa[2] = (short)f2bf(ar[j][2]); pa[3] = (short)f2bf(ar[j][3]); \
        *reinterpret_cast<s16x4*>((LA) + idx) = pa; \
        *reinterpret_cast<u32x2*>((LB) + idx) = br[j]; } }

#define COMPUTE(LA, LB) { _Pragma("unroll") for (int ks = 0; ks < 2; ++ks) { \
        s16x8 a[2], b[8]; \
        _Pragma("unroll") for (int m = 0; m < 2; ++m) { \
            const int row = wid * 32 + m * 16 + lr; \
            const int idx = row * 64 + ((ks * 32 + lg * 8) ^ ((row & 7) << 3)); \
            a[m] = *reinterpret_cast<const s16x8*>((LA) + idx); } \
        _Pragma("unroll") for (int n = 0; n < 8; ++n) { \
            const int out = n * 16 + lr; \
            const int idx = out * 64 + ((ks * 32 + lg * 8) ^ ((out & 7) << 3)); \
            b[n] = *reinterpret_cast<const s16x8*>((LB) + idx); } \
        _Pragma("unroll") for (int n = 0; n < 8; ++n) { \
            acc[0][n] = __builtin_amdgcn_mfma_f32_16x16x32_bf16(a[0], b[n], acc[0][n], 0, 0, 0); \
            acc[1][n] = __builtin_amdgcn_mfma_f32_16x16x32_bf16(a[1], b[n], acc[1][n], 0, 0, 0); } } }

    f32x4 acc[2][8];
#pragma unroll
    for (int m = 0; m < 2; ++m)
#pragma unroll
        for (int n = 0; n < 8; ++n) acc[m][n] = (f32x4)(0.0f);

    // prologue: chunk0 staged; chunk1 loads in flight
    LOADA(0); LOADB(0);
    STAGE(A0, B0);
    LOADA(1); LOADB(1);
    __syncthreads();
    // chunk 1: stage buf1, issue loads2, compute buf0
    STAGE(A1, B1);
    LOADA(2); LOADB(2);
    COMPUTE(A0, B0);
    __syncthreads();
    // chunk 2: stage buf0, issue loads3, compute buf1
    STAGE(A0, B0);
    LOADA(3); LOADB(3);
    COMPUTE(A1, B1);
    __syncthreads();
    // chunk 3: stage buf1, compute buf0
    STAGE(A1, B1);
    COMPUTE(A0, B0);
    __syncthreads();
    // chunk 4: compute buf1
    COMPUTE(A1, B1);
    __syncthreads();   // all COMPUTE done before EP overwrites staging LDS

    // epilogue: acc -> EP (padded, ~4-way b16 write conflicts = cheap)
#pragma unroll
    for (int m = 0; m < 2; ++m) {
#pragma unroll
        for (int n = 0; n < 8; ++n) {
#pragma unroll
            for (int r = 0; r < 4; ++r) {
                const int rl = wid * 32 + m * 16 + lg * 4 + r;
                EP[rl * EW + n * 16 + lr] = f2bf(acc[m][n][r]);
            }
        }
    }
    __syncthreads();
    // row-linear re-read -> fully dense 16B stores
#pragma unroll
    for (int p = 0; p < 8; ++p) {
        const int rl  = p * 16 + (tid >> 4);
        const int ch0 = (tid & 15) * 8;
        const int row = row0 + rl;
        if (row < NODES) {
            const s16x8 v = *reinterpret_cast<const s16x8*>(EP + rl * EW + ch0);
            const long sb = (long)(ch0 >> 6) * ((long)SROW * SLICE_CH);
            *reinterpret_cast<s16x8*>(h_s + sb + (long)row * SLICE_CH + (ch0 & 63)) = v;
        }
    }
#undef LOADA
#undef LOADB
#undef STAGE
#undef COMPUTE
}

// ---------------- Aggregation: 2 slices x 64ch, XCD-quad affine -------------
// (unchanged: ~43us; at the 4-compulsory-64B-sector/edge transaction floor,
// R5(4x32)==R8(2x64) established sector granularity; FETCH == compulsory.)
__global__ __launch_bounds__(320) void gcn_agg(const int* __restrict__ ptr,
                                               const int* __restrict__ idx,
                                               const unsigned short* __restrict__ h_s,
                                               const float* __restrict__ inv_deg,
                                               float* __restrict__ out, int E) {
    const int lane  = threadIdx.x & 63;
    const int wid   = threadIdx.x >> 6;               // 0..4
    const int q     = blockIdx.x & 7;                 // XCD id
    const int slice = q >> 2;                         // 0..1
    const int chunk = (blockIdx.x >> 3) * 4 + (q & 3);  // 0..2499
    const int g     = lane >> 3;                      // node sub-index 0..7
    const int c     = lane & 7;                       // eighth-row 0..7
    const int node  = chunk * 40 + wid * 8 + g;       // 2500*40 = 100000

    const int p0  = ptr[node];
    const int deg = ptr[node + 1] - p0;
    const int Em1 = E - 1;
    const float w = inv_deg[node];

    // preload edge indices: lane c holds edges {c, c+8, c+16, c+24} of node g
    int r[4];
#pragma unroll
    for (int j = 0; j < 4; ++j) {
        int a = p0 + c + 8 * j;
        a = a < Em1 ? a : Em1;
        r[j] = idx[a];
    }

    const unsigned short* hb = h_s + (long)slice * ((long)SROW * SLICE_CH) + c * 8;

    float acc[8];
#pragma unroll
    for (int t = 0; t < 8; ++t) acc[t] = 0.0f;

#pragma unroll
    for (int e = 0; e < 32; ++e) {
        // edge e of node g is held by lane g*8 + (e&7), register e>>3
        int s = __shfl(r[e >> 3], (lane & 56) | (e & 7));
        s = e < deg ? s : NODES;                      // zero row: no predication
        const u32x4 v = *reinterpret_cast<const u32x4*>(hb + (long)s * SLICE_CH);
        acc[0] += lo2f(v[0]); acc[1] += hi2f(v[0]);
        acc[2] += lo2f(v[1]); acc[3] += hi2f(v[1]);
        acc[4] += lo2f(v[2]); acc[5] += hi2f(v[2]);
        acc[6] += lo2f(v[3]); acc[7] += hi2f(v[3]);
    }

    float* op = out + (long)node * DOUT + slice * SLICE_CH + c * 8;
    f32x4 o0, o1;
    o0[0] = acc[0] * w; o0[1] = acc[1] * w; o0[2] = acc[2] * w; o0[3] = acc[3] * w;
    o1[0] = acc[4] * w; o1[1] = acc[5] * w; o1[2] = acc[6] * w; o1[3] = acc[7] * w;
    *reinterpret_cast<f32x4*>(op) = o0;
    *reinterpret_cast<f32x4*>(op + 4) = o1;
}

extern "C" void kernel_launch(void* const* d_in, const int* in_sizes, int n_in,
                              void* d_out, int out_size, void* d_ws, size_t ws_size,
                              hipStream_t stream) {
    const float* x   = (const float*)d_in[0];
    const float* W   = (const float*)d_in[1];
    const int*   ptr = (const int*)d_in[2];
    const int*   idx = (const int*)d_in[3];
    // d_in[4] (dst) unused: CSR ptr encodes destinations.
    float* out = (float*)d_out;
    const int E = in_sizes[3];

    char* ws = (char*)d_ws;
    unsigned short* wsW     = (unsigned short*)ws;               // 64 KB
    float*          inv_deg = (float*)(ws + (64 << 10));         // 400 KB
    unsigned short* h_s     = (unsigned short*)(ws + (1 << 20)); // 2*SROW*64*2B

    gcn_prep<<<391, 256, 0, stream>>>(W, ptr, wsW, inv_deg, h_s);
    // 782 blocks x (128 rows x 128 cols) tile; 4 waves/block, dbuf LDS
    gcn_gemm<<<782, 256, 0, stream>>>(x, wsW, h_s);
    // 625 x 8 blocks: XCD q=blockIdx&7 -> slice q>>2, chunk=(blockIdx>>3)*4+(q&3)
    gcn_agg<<<5000, 320, 0, stream>>>(ptr, idx, h_s, inv_deg, out, E);
}